// Round 8
// baseline (270.185 us; speedup 1.0000x reference)
//
#include <hip/hip_runtime.h>

// ConvCrossAttention on MI355X (gfx950), bf16 MFMA implementation.
// R8: big convs restructured: pixel region resident in LDS (9-tap halo reuse),
//     weights in a 4-deep ring with counted vmcnt (never drained in-loop),
//     BK=32, 1 barrier/step, 3 blocks/CU. K/V convs back to standalone 32KB
//     launch. attn unchanged from R7.

typedef __attribute__((ext_vector_type(8))) short short8;
typedef __attribute__((ext_vector_type(4))) float f32x4;
typedef unsigned short us;

__device__ __forceinline__ float bf2f(us u) {
  union { unsigned int i; float f; } v; v.i = ((unsigned int)u) << 16; return v.f;
}
__device__ __forceinline__ us f2bf(float f) {
  union { float f; unsigned int i; } v; v.f = f;
  unsigned int x = v.i;
  return (us)((x + 0x7fffu + ((x >> 16) & 1u)) >> 16);
}

typedef __attribute__((address_space(3))) unsigned int as3_uint;
typedef const __attribute__((address_space(1))) unsigned int as1_uint;
__device__ __forceinline__ void gload16(const us* g, us* l) {
  __builtin_amdgcn_global_load_lds((as1_uint*)g, (as3_uint*)l, 16, 0, 0);
}
__device__ __forceinline__ unsigned int cvt_pk_bf16(float a, float b) {
  unsigned int r;
  asm("v_cvt_pk_bf16_f32 %0, %1, %2" : "=v"(r) : "v"(a), "v"(b));
  return r;
}
__device__ __forceinline__ float fast_exp2(float x) {
  float r;
  asm("v_exp_f32 %0, %1" : "=v"(r) : "v"(x));
  return r;
}

// ================================================= fused prep kernel (unchanged)
__device__ __forceinline__ void transpose_body(
    const float* __restrict__ in, us* __restrict__ outT,
    int b, int y, int ci0, int H, int W, int logW) {
  const int C = 512;
  int padW = W + 2, Ppad = (H + 2) * padW;
  __shared__ float tile[64][65];
  int nt = W * 64;
  for (int idx = threadIdx.x; idx < nt; idx += 256) {
    int ci = idx >> logW, x = idx & (W - 1);
    tile[ci][x] = in[(((size_t)b * C + ci0 + ci) * H + y) * W + x];
  }
  __syncthreads();
  int nt2 = W * 32;
  for (int idx = threadIdx.x; idx < nt2; idx += 256) {
    int px = idx >> 5, c2 = idx & 31;
    unsigned int val = (unsigned int)f2bf(tile[c2 * 2][px]) |
                       ((unsigned int)f2bf(tile[c2 * 2 + 1][px]) << 16);
    *(unsigned int*)(outT + ((size_t)b * Ppad + (size_t)(y + 1) * padW + (px + 1)) * C +
                     ci0 + c2 * 2) = val;
  }
}

__global__ __launch_bounds__(256) void prep_all(
    const float* __restrict__ x, const float* __restrict__ cross,
    const float* __restrict__ wq, const float* __restrict__ wk,
    const float* __restrict__ wv, const float* __restrict__ wo,
    const float* __restrict__ lq1, const float* __restrict__ lq2,
    const float* __restrict__ lk1, const float* __restrict__ lk2,
    us* __restrict__ xpadT, us* __restrict__ cpadT, us* __restrict__ apad,
    us* __restrict__ oq, us* __restrict__ ok, us* __restrict__ ov,
    us* __restrict__ oo, float* __restrict__ lam) {
  int bid = blockIdx.x, tid = threadIdx.x;
  if (bid < 326) {
    int g = bid * 4 + (tid >> 6);
    int t = tid & 63;
    us* base; int W, b, i;
    if (g < 520)      { base = xpadT; W = 64; b = g >= 260; i = g - b * 260; }
    else if (g < 784) { base = cpadT; W = 32; int gg = g - 520; b = gg >= 132; i = gg - b * 132; }
    else              { base = apad; W = 64; int gg = g - 784; b = gg >= 260; i = gg - b * 260; }
    int padW = W + 2, nb = 2 * padW;
    int yy, xx;
    if (i < padW)    { yy = 0; xx = i; }
    else if (i < nb) { yy = W + 1; xx = i - padW; }
    else             { int j = i - nb; yy = 1 + (j >> 1); xx = (j & 1) * (W + 1); }
    size_t p = ((size_t)b * padW * padW + (size_t)yy * padW + xx) * 512 + t * 8;
    *(int4*)(base + p) = make_int4(0, 0, 0, 0);
  } else if (bid < 1350) {
    int i = bid - 326;
    transpose_body(x, xpadT, i >> 9, (i >> 3) & 63, (i & 7) * 64, 64, 64, 6);
  } else if (bid < 1862) {
    int i = bid - 1350;
    transpose_body(cross, cpadT, i >> 8, (i >> 3) & 31, (i & 7) * 64, 32, 32, 5);
  } else if (bid < 4166) {
    int blk = bid - 1862;
    const float* src; us* dst; int Cout, co;
    if (blk < 1024)      { src = wq; dst = oq; Cout = 1024; co = blk; }
    else if (blk < 1536) { src = wk; dst = ok; Cout = 512;  co = blk - 1024; }
    else if (blk < 1792) { src = wv; dst = ov; Cout = 256;  co = blk - 1536; }
    else                 { src = wo; dst = oo; Cout = 512;  co = blk - 1792; }
    __shared__ us l[4608];
    const float* s0 = src + (size_t)co * 4608;
#pragma unroll
    for (int k = 0; k < 18; ++k) { int i = k * 256 + tid; l[i] = f2bf(s0[i]); }
    __syncthreads();
#pragma unroll
    for (int k = 0; k < 9; ++k) {
      int j = k * 256 + tid;
      int t = j >> 8, c2 = j & 255;
      unsigned int val = (unsigned int)l[(c2 * 2) * 9 + t] |
                         ((unsigned int)l[(c2 * 2 + 1) * 9 + t] << 16);
      *(unsigned int*)(dst + (size_t)t * Cout * 512 + (size_t)co * 512 + c2 * 2) = val;
    }
  } else {
    int h = tid >> 5, d = tid & 31;
    float s1 = lq1[h * 64 + d] * lk1[h * 64 + d] +
               lq1[h * 64 + d + 32] * lk1[h * 64 + d + 32];
    float s2 = lq2[h * 64 + d] * lk2[h * 64 + d] +
               lq2[h * 64 + d + 32] * lk2[h * 64 + d + 32];
    for (int m = 16; m; m >>= 1) {
      s1 += __shfl_xor(s1, m);
      s2 += __shfl_xor(s2, m);
    }
    if (d == 0) lam[h] = -(expf(s1) - expf(s2) + 0.2f);
  }
}

// ================================================= resident-pixel conv pipeline
// MODE 0 (Q): tile 128px x 128co; pixels resident (A/M side), weights ring (B/N);
//             out bf16 [B][4096][1024] with fused RoPE.
// MODE 1 (OUT): tile 128co x 64px; weights ring (A/M side), pixels resident (B/N);
//             out f32 [B][512][4096], px-coalesced.
// 144 steps (16 ci-chunks x 9 taps), BK=32, 4-deep weight ring, counted vmcnt.
template <int MODE>
__global__ __launch_bounds__(256) void conv_main(
    const us* __restrict__ pix,   // padded pixels [B][4356][512]
    const us* __restrict__ wp,    // [9][Cout][512]
    us* __restrict__ outb, float* __restrict__ outf) {
  constexpr int NR = (MODE == 0) ? 4 : 2;
  constexpr int Cout = (MODE == 0) ? 1024 : 512;
  constexpr int RROWS = (MODE == 0) ? 264 : 198;   // 4 (2) padded rows x 66
  constexpr int AROUNDS = (MODE == 0) ? 5 : 4;     // 64-row stage rounds (clamped)
  int bid = blockIdx.x;                            // 512 blocks
  int v = (bid & 7) * 64 + (bid >> 3);             // XCD swizzle
  int b, p0, co0;
  if (MODE == 0) { p0 = ((v >> 3) & 31) * 128; co0 = (v & 7) * 128; b = v >> 8; }
  else           { p0 = (v & 63) * 64; co0 = ((v >> 6) & 3) * 128; b = v >> 8; }
  int tid = threadIdx.x;
  int wave = tid >> 6, lane = tid & 63, l15 = lane & 15, hi4 = lane >> 4;
  int wr = wave >> 1, wc = wave & 1;

  __shared__ __align__(16) us Dbuf[4][128 * 32];                    // weight ring, 32 KB
  __shared__ __align__(16) us Res[(MODE == 0 ? 320 : 256) * 32];    // pixel region

  f32x4 acc[4][NR];
#pragma unroll
  for (int m = 0; m < 4; ++m)
#pragma unroll
    for (int n = 0; n < NR; ++n) acc[m][n] = (f32x4){0.f, 0.f, 0.f, 0.f};

  int y0 = p0 >> 6;
  const us* resg = pix + ((size_t)b * 4356 + (size_t)y0 * 66) * 512;
  int srow = wave * 16 + (lane >> 2);   // staging row within 64-row round
  int sg = lane & 3;                    // staging ci-group (linear dest)

  auto stageRes = [&](int c) {
#pragma unroll
    for (int ar = 0; ar < AROUNDS; ++ar) {
      int row = ar * 64 + srow;
      int rowc = row < RROWS ? row : RROWS - 1;   // clamp: uniform instr count
      gload16(resg + (size_t)rowc * 512 + c * 32 + ((sg ^ (rowc & 3)) * 8),
              &Res[(ar * 64 + wave * 16) * 32]);
    }
  };
  auto stageD = [&](int buf, int t, int c) {
#pragma unroll
    for (int dr = 0; dr < 2; ++dr) {
      int row = dr * 64 + srow;
      gload16(wp + ((size_t)t * Cout + co0 + row) * 512 + c * 32 + ((sg ^ (row & 3)) * 8),
              &Dbuf[buf][(dr * 64 + wave * 16) * 32]);
    }
  };

  stageRes(0);
  stageD(0, 0, 0);
  stageD(1, 1, 0);

  for (int c = 0; c < 16; ++c) {
#pragma unroll
    for (int t = 0; t < 9; ++t) {
      int s = c * 9 + t;
      int sn = s + 2;
      if (sn < 144) stageD((c + t + 2) & 3, sn % 9, sn / 9);
      if (s == 143)
        asm volatile("s_waitcnt vmcnt(0)" ::: "memory");
      else if (s == 142 || (t == 0 && s))
        asm volatile("s_waitcnt vmcnt(2)" ::: "memory");
      else
        asm volatile("s_waitcnt vmcnt(4)" ::: "memory");
      __builtin_amdgcn_s_barrier();
      __builtin_amdgcn_sched_barrier(0);

      int ky = (t * 11) >> 5, kx = t - ky * 3;
      const us* db = &Dbuf[(c + t) & 3][0];
      short8 af[4], bf[NR];
      if (MODE == 0) {
#pragma unroll
        for (int m = 0; m < 4; ++m) {
          int row = (wr + ky) * 66 + m * 16 + l15 + kx;
          af[m] = *(const short8*)&Res[row * 32 + ((hi4 ^ (row & 3)) * 8)];
        }
#pragma unroll
        for (int n = 0; n < NR; ++n) {
          int row = wc * 64 + n * 16 + l15;
          bf[n] = *(const short8*)(db + row * 32 + ((hi4 ^ (row & 3)) * 8));
        }
      } else {
#pragma unroll
        for (int m = 0; m < 4; ++m) {
          int row = wr * 64 + m * 16 + l15;
          af[m] = *(const short8*)(db + row * 32 + ((hi4 ^ (row & 3)) * 8));
        }
#pragma unroll
        for (int n = 0; n < NR; ++n) {
          int row = ky * 66 + wc * 32 + n * 16 + l15 + kx;
          bf[n] = *(const short8*)&Res[row * 32 + ((hi4 ^ (row & 3)) * 8)];
        }
      }
#pragma unroll
      for (int m = 0; m < 4; ++m)
#pragma unroll
        for (int n = 0; n < NR; ++n)
          acc[m][n] = __builtin_amdgcn_mfma_f32_16x16x32_bf16(af[m], bf[n], acc[m][n], 0, 0, 0);

      if (t == 8 && c < 15) {
        __builtin_amdgcn_s_barrier();        // all waves done reading Res(c)
        __builtin_amdgcn_sched_barrier(0);
        stageRes(c + 1);
      }
    }
  }

  if (MODE == 0) {
    // RoPE epilogue: pairs (2j,2j+1) along co sit in adjacent lanes
    int par = lane & 1;
#pragma unroll
    for (int n = 0; n < NR; ++n) {
      int co = co0 + wc * 64 + n * 16 + l15;
      int j = (co & 127) >> 1;
      float th = exp2f(-(float)j * 0.20762050593f);
      float sth, cth;
      sincosf(th, &sth, &cth);
#pragma unroll
      for (int m = 0; m < 4; ++m) {
        int pxb = p0 + wr * 64 + m * 16 + hi4 * 4;
        float s0, c0;
        sincosf((float)pxb * th, &s0, &c0);
#pragma unroll
        for (int r = 0; r < 4; ++r) {
          float xv = acc[m][n][r];
          float ov = __shfl_xor(xv, 1);
          float y = par ? fmaf(ov, s0, xv * c0) : fmaf(xv, c0, -ov * s0);
          outb[((size_t)b * 4096 + (pxb + r)) * 1024 + co] = f2bf(y);
          float c1 = c0 * cth - s0 * sth;
          s0 = fmaf(c0, sth, s0 * cth);
          c0 = c1;
        }
      }
    }
  } else {
#pragma unroll
    for (int m = 0; m < 4; ++m)
#pragma unroll
      for (int n = 0; n < NR; ++n)
#pragma unroll
        for (int r = 0; r < 4; ++r) {
          int co = co0 + wr * 64 + m * 16 + hi4 * 4 + r;
          int px = p0 + wc * 32 + n * 16 + l15;
          outf[((size_t)b * 512 + co) * 4096 + px] = acc[m][n][r];
        }
  }
}

// ================================================= 64^2 conv body (K,V), 32KB LDS
template <int TRANS_OUT, int ROPE>
__device__ __forceinline__ void conv64_body(
    const us* __restrict__ inT, const us* __restrict__ wp,
    us* __restrict__ out, int Cout, int logCoT, int bid, int ngrid, us* sh) {
  int nchunk = ngrid >> 3;
  int v = (bid & 7) * nchunk + (bid >> 3);
  int yt = v & 15;
  int cot = (v >> 4) & ((1 << logCoT) - 1);
  int b = v >> (4 + logCoT);
  int p0 = yt * 64, co0 = cot * 64;
  const int W = 32, logW = 5, padW = 34, HW = 1024;
  int tid = threadIdx.x;
  int wave = tid >> 6, lane = tid & 63, l15 = lane & 15, hi4 = lane >> 4;
  f32x4 acc[4];
#pragma unroll
  for (int i = 0; i < 4; ++i) acc[i] = (f32x4){0.f, 0.f, 0.f, 0.f};

  int arow[2], brow[2];
#pragma unroll
  for (int c = 0; c < 2; ++c) {
    int row = (wave * 2 + c) * 8 + (lane >> 3);
    int g = (lane & 7) ^ (row & 7);
    int px = p0 + row;
    int y = px >> logW, x = px & (W - 1);
    arow[c] = (y * padW + x) * 512 + g * 8;
    brow[c] = (co0 + row) * 512 + g * 8;
  }
  int gb[2];
#pragma unroll
  for (int ks = 0; ks < 2; ++ks) gb[ks] = ((ks * 4 + hi4) ^ (l15 & 7)) * 8;

  const us* abase = inT + (size_t)b * padW * padW * 512;

  auto stage = [&](int buf, int s) {
    int tn = s >> 3, ci = (s & 7) << 6;
    int ky = (tn * 11) >> 5, kx = tn - ky * 3;
    const us* as = abase + (ky * padW + kx) * 512 + ci;
    const us* bs = wp + (size_t)tn * Cout * 512 + ci;
    us* la = sh + buf * 8192;
    us* lb = la + 4096;
#pragma unroll
    for (int c = 0; c < 2; ++c) {
      gload16(as + arow[c], la + (wave * 2 + c) * 512);
      gload16(bs + brow[c], lb + (wave * 2 + c) * 512);
    }
  };

  stage(0, 0);
  __syncthreads();
  for (int s = 0; s < 72; ++s) {
    int cur = s & 1;
    if (s < 71) stage(cur ^ 1, s + 1);
    const us* la = sh + cur * 8192;
    const us* lb = la + 4096;
#pragma unroll
    for (int ks = 0; ks < 2; ++ks) {
      short8 bf = *(const short8*)(lb + (16 * wave + l15) * 64 + gb[ks]);
#pragma unroll
      for (int i = 0; i < 4; ++i) {
        short8 af = *(const short8*)(la + (i * 16 + l15) * 64 + gb[ks]);
        acc[i] = __builtin_amdgcn_mfma_f32_16x16x32_bf16(af, bf, acc[i], 0, 0, 0);
      }
    }
    __syncthreads();
  }
  if (ROPE) {
    int co = co0 + 16 * wave + l15;
    int j = (co & 127) >> 1;
    float th = exp2f(-(float)j * 0.20762050593f);
    float sth, cth;
    sincosf(th, &sth, &cth);
    int par = lane & 1;
#pragma unroll
    for (int i = 0; i < 4; ++i) {
      int pxb = p0 + i * 16 + hi4 * 4;
      float s0, c0;
      sincosf((float)pxb * th, &s0, &c0);
#pragma unroll
      for (int r = 0; r < 4; ++r) {
        float xv = acc[i][r];
        float ov = __shfl_xor(xv, 1);
        float y = par ? fmaf(ov, s0, xv * c0) : fmaf(xv, c0, -ov * s0);
        out[((size_t)b * HW + (pxb + r)) * Cout + co] = f2bf(y);
        float c1 = c0 * cth - s0 * sth;
        s0 = fmaf(c0, sth, s0 * cth);
        c0 = c1;
      }
    }
  } else {
#pragma unroll
    for (int i = 0; i < 4; ++i)
#pragma unroll
      for (int r = 0; r < 4; ++r) {
        int px = TRANS_OUT ? (p0 + (hi4 * 4 + r) * 4 + i)  // sigma(k)=(k%16)*4+k/16
                           : (p0 + i * 16 + hi4 * 4 + r);
        int co = co0 + 16 * wave + l15;
        us val = f2bf(acc[i][r]);
        if (TRANS_OUT)
          out[((size_t)b * Cout + co) * HW + px] = val;
        else
          out[((size_t)b * HW + px) * Cout + co] = val;
      }
  }
}

__global__ __launch_bounds__(256) void conv64_all(
    const us* __restrict__ cpadT, const us* __restrict__ wkp,
    const us* __restrict__ wvp, us* __restrict__ kb, us* __restrict__ vT) {
  __shared__ __align__(16) us sh[2][2][64][64];  // 32 KB
  int bid = blockIdx.x;
  if (bid < 256) conv64_body<0, 1>(cpadT, wkp, kb, 512, 3, bid, 256, &sh[0][0][0][0]);
  else           conv64_body<1, 0>(cpadT, wvp, vT, 256, 2, bid - 256, 128, &sh[0][0][0][0]);
}

// ================================================= differential GQA attention + RMSNorm
__global__ __launch_bounds__(256) void attn_kernel(
    const us* __restrict__ qb, const us* __restrict__ kb,
    const us* __restrict__ vT, const float* __restrict__ lam,
    us* __restrict__ apad) {
  int qt = blockIdx.x, h = blockIdx.y, b = blockIdx.z;
  int kvh = h >> 1;
  int tid = threadIdx.x;
  int wave = tid >> 6, lane = tid & 63, l15 = lane & 15, hi4 = lane >> 4;
  __shared__ __align__(16) us Klds[2][8192];   // [buf][64 k rows][128 d]
  __shared__ __align__(16) us Vlds[2][4096];   // [buf][64 dv rows][64 k']
  __shared__ __align__(16) us Plds[4][16][72];

  int q0 = qt * 128;
  short8 qf[2][2][2];  // [mf][m][ks]
  {
    const us* qsrc =
        qb + ((size_t)(b * 4096 + q0 + wave * 32 + l15)) * 1024 + h * 128 + hi4 * 8;
#pragma unroll
    for (int mf = 0; mf < 2; ++mf)
#pragma unroll
      for (int m = 0; m < 2; ++m)
#pragma unroll
        for (int ks = 0; ks < 2; ++ks)
          qf[mf][m][ks] = *(const short8*)(qsrc + mf * 16384 + m * 64 + ks * 32);
  }

  float sumd[2][2][4];
  f32x4 accO[2][2][4];
#pragma unroll
  for (int mf = 0; mf < 2; ++mf)
#pragma unroll
    for (int m = 0; m < 2; ++m)
#pragma unroll
      for (int r = 0; r < 4; ++r) {
        sumd[mf][m][r] = 0.f;
        accO[mf][m][r] = (f32x4){0.f, 0.f, 0.f, 0.f};
      }
  float lamh = lam[h];

  const us* kbase0 = kb + (size_t)b * 524288 + kvh * 128;
  const us* vbase0 = vT + ((size_t)(b * 256 + kvh * 64)) * 1024;
  int krow[4], vrow[2];
#pragma unroll
  for (int c = 0; c < 4; ++c) {
    int row = (wave * 4 + c) * 4 + hi4;
    int g = (l15 & 8) | ((l15 & 7) ^ (row & 7));
    krow[c] = row * 512 + g * 8;
  }
#pragma unroll
  for (int c = 0; c < 2; ++c) {
    int row = (wave * 2 + c) * 8 + (lane >> 3);
    int g = (lane & 7) ^ (row & 7);
    vrow[c] = row * 1024 + g * 8;
  }
  int kg0[2], kg1[2], vg[2];
#pragma unroll
  for (int m = 0; m < 2; ++m) {
    kg0[m] = (m * 8 | (hi4 ^ (l15 & 7))) * 8;
    kg1[m] = (m * 8 | ((4 + hi4) ^ (l15 & 7))) * 8;
  }
#pragma unroll
  for (int ks = 0; ks < 2; ++ks) vg[ks] = ((ks * 4 + hi4) ^ (l15 & 7)) * 8;

  auto stage = [&](int buf, int kt2) {
    const us* kk = kbase0 + (size_t)kt2 * 32768;
    const us* vv = vbase0 + kt2 * 64;
#pragma unroll
    for (int c = 0; c < 4; ++c)
      gload16(kk + krow[c], &Klds[buf][(wave * 4 + c) * 512]);
#pragma unroll
    for (int c = 0; c < 2; ++c)
      gload16(vv + vrow[c], &Vlds[buf][(wave * 2 + c) * 512]);
  };

  const float cexp = 0.18033688f;  // 0.125 * log2(e)
  stage(0, 0);
  for (int kt = 0; kt < 16; ++kt) {
    int cur = kt & 1;
    if (kt < 15) {
      stage(cur ^ 1, kt + 1);
      asm volatile("s_waitcnt vmcnt(6)" ::: "memory");
    } else {
      asm volatile("s_waitcnt vmcnt(0)" ::: "memory");
    }
    __builtin_amdgcn_s_barrier();
    __builtin_amdgcn_sched_barrier(0);

    short8 vf[2][4];
#pragma unroll
    for (int ks = 0; ks < 2; ++ks)
#pragma unroll
      for (int nf = 0; nf < 4; ++nf)
        vf[ks][nf] = *(const short8*)&Vlds[cur][(nf * 16 + l15) * 64 + vg[ks]];

#pragma unroll
    for (int m = 0; m < 2; ++m) {
      short8 kf[4][2];
#pragma unroll
      for (int nf = 0; nf < 4; ++nf) {
        kf[nf][0] = *(const short8*)&Klds[cur][(nf * 16 + l15) * 128 + kg0[m]];
        kf[nf][1] = *(const short8*)&Klds[cur][(nf * 16 + l15) * 128 + kg1[m]];
      }
#pragma unroll
      for (int mf = 0; mf < 2; ++mf) {
        f32x4 s[4];
        __builtin_amdgcn_s_setprio(1);
#pragma unroll
        for (int nf = 0; nf < 4; ++nf) {
          f32x4 z = (f32x4){0.f, 0.f, 0.f, 0.f};
          z = __builtin_amdgcn_mfma_f32_16x16x32_bf16(qf[mf][m][0], kf[nf][0], z, 0, 0, 0);
          z = __builtin_amdgcn_mfma_f32_16x16x32_bf16(qf[mf][m][1], kf[nf][1], z, 0, 0, 0);
          s[nf] = z;
        }
        __builtin_amdgcn_s_setprio(0);
#pragma unroll
        for (int r = 0; r < 4; ++r) {
          float p0 = fast_exp2(s[0][r] * cexp);
          float p1 = fast_exp2(s[1][r] * cexp);
          float p2 = fast_exp2(s[2][r] * cexp);
          float p3 = fast_exp2(s[3][r] * cexp);
          sumd[mf][m][r] += (p0 + p1) + (p2 + p3);
          unsigned int w0 = cvt_pk_bf16(p0, p1);
          unsigned int w1 = cvt_pk_bf16(p2, p3);
          *(uint2*)&Plds[wave][hi4 * 4 + r][l15 * 4] = make_uint2(w0, w1);
        }
        __builtin_amdgcn_s_setprio(1);
#pragma unroll
        for (int ks = 0; ks < 2; ++ks) {
          short8 pf = *(const short8*)&Plds[wave][l15][ks * 32 + hi4 * 8];
#pragma unroll
          for (int nf = 0; nf < 4; ++nf)
            accO[mf][m][nf] =
                __builtin_amdgcn_mfma_f32_16x16x32_bf16(pf, vf[ks][nf], accO[mf][m][nf], 0, 0, 0);
        }
        __builtin_amdgcn_s_setprio(0);
      }
    }
    asm volatile("s_waitcnt lgkmcnt(0)" ::: "memory");
    __builtin_amdgcn_s_barrier();
    __builtin_amdgcn_sched_barrier(0);
  }

  // epilogue: denom reduce, combine mults, RMSNorm, scale 0.8
#pragma unroll
  for (int mf = 0; mf < 2; ++mf)
#pragma unroll
    for (int m = 0; m < 2; ++m)
#pragma unroll
      for (int r = 0; r < 4; ++r) {
        float sx = sumd[mf][m][r];
        sx += __shfl_xor(sx, 1);
        sx += __shfl_xor(sx, 2);
        sx += __shfl_xor(sx, 4);
        sx += __shfl_xor(sx, 8);
        sumd[mf][m][r] = sx;
      }
#pragma unroll
  for (int mf = 0; mf < 2; ++mf)
#pragma unroll
    for (int r = 0; r < 4; ++r) {
      float inv0 = 1.f / sumd[mf][0][r];
      float inv1 = lamh / sumd[mf][1][r];
      float comb[4];
      float ss = 0.f;
#pragma unroll
      for (int nf = 0; nf < 4; ++nf) {
        comb[nf] = accO[mf][0][nf][r] * inv0 + accO[mf][1][nf][r] * inv1;
        ss += comb[nf] * comb[nf];
      }
      ss += __shfl_xor(ss, 1);
      ss += __shfl_xor(ss, 2);
      ss += __shfl_xor(ss, 4);
      ss += __shfl_xor(ss, 8);
      float sc = rsqrtf(ss * (1.f / 64.f) + 1e-8f) * 0.8f;
      int q = q0 + wave * 32 + mf * 16 + hi4 * 4 + r;
      int y = q >> 6, x = q & 63;
      size_t oaddr = ((size_t)b * 4356 + (size_t)(y + 1) * 66 + (x + 1)) * 512 + h * 64;
#pragma unroll
      for (int nf = 0; nf < 4; ++nf) apad[oaddr + nf * 16 + l15] = f2bf(comb[nf] * sc);
    }
}

// ============================================================== launch
extern "C" void kernel_launch(void* const* d_in, const int* in_sizes, int n_in,
                              void* d_out, int out_size, void* d_ws, size_t ws_size,
                              hipStream_t stream) {
  const float* x     = (const float*)d_in[0];
  const float* cross = (const float*)d_in[1];
  const float* wq    = (const float*)d_in[2];
  const float* wk    = (const float*)d_in[3];
  const float* wv    = (const float*)d_in[4];
  const float* wo    = (const float*)d_in[5];
  const float* lq1   = (const float*)d_in[6];
  const float* lq2   = (const float*)d_in[7];
  const float* lk1   = (const float*)d_in[8];
  const float* lk2   = (const float*)d_in[9];
  float* out = (float*)d_out;

  char* ws = (char*)d_ws;
  size_t off = 0;
  auto nxt = [&](size_t bytes) { char* p = ws + off; off += bytes; return p; };
  us* xpadT = (us*)nxt(8921088);   // [2][4356][512] bf16
  us* cpadT = (us*)nxt(2367488);   // [2][1156][512] bf16
  us* apad  = (us*)nxt(8921088);   // [2][4356][512] bf16
  us* wqp = (us*)nxt(9437184);     // [9][1024][512]
  us* wkp = (us*)nxt(4718592);     // [9][512][512]
  us* wvp = (us*)nxt(2359296);     // [9][256][512]
  us* wop = (us*)nxt(4718592);     // [9][512][512]
  us* qb  = (us*)nxt(16777216);    // [2][4096][1024] (rope'd)
  us* kb  = (us*)nxt(2097152);     // [2][1024][512]  (rope'd)
  us* vT  = (us*)nxt(1048576);     // [2][256][1024] (sigma-permuted along k)
  float* lam = (float*)nxt(256);   // [8]
  (void)ws_size; (void)in_sizes; (void)n_in; (void)out_size;

  prep_all<<<4167, 256, 0, stream>>>(x, cross, wq, wk, wv, wo,
                                     lq1, lq2, lk1, lk2,
                                     xpadT, cpadT, apad, wqp, wkp, wvp, wop, lam);
  conv64_all<<<384, 256, 0, stream>>>(cpadT, wkp, wvp, kb, vT);
  conv_main<0><<<512, 256, 0, stream>>>(xpadT, wqp, qb, nullptr);
  attn_kernel<<<dim3(32, 8, 2), 256, 0, stream>>>(qb, kb, vT, lam, apad);
  conv_main<1><<<512, 256, 0, stream>>>(apad, wop, nullptr, out);
}

// Round 9
// 266.301 us; speedup vs baseline: 1.0146x; 1.0146x over previous
//
#include <hip/hip_runtime.h>

// ConvCrossAttention on MI355X (gfx950), bf16 MFMA implementation.
// R9: R8 + LDS bank-conflict fix in conv_main: swizzle g(row)=(row>>1)&3
//     (was row&3) on BOTH staging source and reads -> 2-way (free) instead
//     of 4-way conflicts on 64B-row tiles. Everything else unchanged.

typedef __attribute__((ext_vector_type(8))) short short8;
typedef __attribute__((ext_vector_type(4))) float f32x4;
typedef unsigned short us;

__device__ __forceinline__ float bf2f(us u) {
  union { unsigned int i; float f; } v; v.i = ((unsigned int)u) << 16; return v.f;
}
__device__ __forceinline__ us f2bf(float f) {
  union { float f; unsigned int i; } v; v.f = f;
  unsigned int x = v.i;
  return (us)((x + 0x7fffu + ((x >> 16) & 1u)) >> 16);
}

typedef __attribute__((address_space(3))) unsigned int as3_uint;
typedef const __attribute__((address_space(1))) unsigned int as1_uint;
__device__ __forceinline__ void gload16(const us* g, us* l) {
  __builtin_amdgcn_global_load_lds((as1_uint*)g, (as3_uint*)l, 16, 0, 0);
}
__device__ __forceinline__ unsigned int cvt_pk_bf16(float a, float b) {
  unsigned int r;
  asm("v_cvt_pk_bf16_f32 %0, %1, %2" : "=v"(r) : "v"(a), "v"(b));
  return r;
}
__device__ __forceinline__ float fast_exp2(float x) {
  float r;
  asm("v_exp_f32 %0, %1" : "=v"(r) : "v"(x));
  return r;
}

// ================================================= fused prep kernel (unchanged)
__device__ __forceinline__ void transpose_body(
    const float* __restrict__ in, us* __restrict__ outT,
    int b, int y, int ci0, int H, int W, int logW) {
  const int C = 512;
  int padW = W + 2, Ppad = (H + 2) * padW;
  __shared__ float tile[64][65];
  int nt = W * 64;
  for (int idx = threadIdx.x; idx < nt; idx += 256) {
    int ci = idx >> logW, x = idx & (W - 1);
    tile[ci][x] = in[(((size_t)b * C + ci0 + ci) * H + y) * W + x];
  }
  __syncthreads();
  int nt2 = W * 32;
  for (int idx = threadIdx.x; idx < nt2; idx += 256) {
    int px = idx >> 5, c2 = idx & 31;
    unsigned int val = (unsigned int)f2bf(tile[c2 * 2][px]) |
                       ((unsigned int)f2bf(tile[c2 * 2 + 1][px]) << 16);
    *(unsigned int*)(outT + ((size_t)b * Ppad + (size_t)(y + 1) * padW + (px + 1)) * C +
                     ci0 + c2 * 2) = val;
  }
}

__global__ __launch_bounds__(256) void prep_all(
    const float* __restrict__ x, const float* __restrict__ cross,
    const float* __restrict__ wq, const float* __restrict__ wk,
    const float* __restrict__ wv, const float* __restrict__ wo,
    const float* __restrict__ lq1, const float* __restrict__ lq2,
    const float* __restrict__ lk1, const float* __restrict__ lk2,
    us* __restrict__ xpadT, us* __restrict__ cpadT, us* __restrict__ apad,
    us* __restrict__ oq, us* __restrict__ ok, us* __restrict__ ov,
    us* __restrict__ oo, float* __restrict__ lam) {
  int bid = blockIdx.x, tid = threadIdx.x;
  if (bid < 326) {
    int g = bid * 4 + (tid >> 6);
    int t = tid & 63;
    us* base; int W, b, i;
    if (g < 520)      { base = xpadT; W = 64; b = g >= 260; i = g - b * 260; }
    else if (g < 784) { base = cpadT; W = 32; int gg = g - 520; b = gg >= 132; i = gg - b * 132; }
    else              { base = apad; W = 64; int gg = g - 784; b = gg >= 260; i = gg - b * 260; }
    int padW = W + 2, nb = 2 * padW;
    int yy, xx;
    if (i < padW)    { yy = 0; xx = i; }
    else if (i < nb) { yy = W + 1; xx = i - padW; }
    else             { int j = i - nb; yy = 1 + (j >> 1); xx = (j & 1) * (W + 1); }
    size_t p = ((size_t)b * padW * padW + (size_t)yy * padW + xx) * 512 + t * 8;
    *(int4*)(base + p) = make_int4(0, 0, 0, 0);
  } else if (bid < 1350) {
    int i = bid - 326;
    transpose_body(x, xpadT, i >> 9, (i >> 3) & 63, (i & 7) * 64, 64, 64, 6);
  } else if (bid < 1862) {
    int i = bid - 1350;
    transpose_body(cross, cpadT, i >> 8, (i >> 3) & 31, (i & 7) * 64, 32, 32, 5);
  } else if (bid < 4166) {
    int blk = bid - 1862;
    const float* src; us* dst; int Cout, co;
    if (blk < 1024)      { src = wq; dst = oq; Cout = 1024; co = blk; }
    else if (blk < 1536) { src = wk; dst = ok; Cout = 512;  co = blk - 1024; }
    else if (blk < 1792) { src = wv; dst = ov; Cout = 256;  co = blk - 1536; }
    else                 { src = wo; dst = oo; Cout = 512;  co = blk - 1792; }
    __shared__ us l[4608];
    const float* s0 = src + (size_t)co * 4608;
#pragma unroll
    for (int k = 0; k < 18; ++k) { int i = k * 256 + tid; l[i] = f2bf(s0[i]); }
    __syncthreads();
#pragma unroll
    for (int k = 0; k < 9; ++k) {
      int j = k * 256 + tid;
      int t = j >> 8, c2 = j & 255;
      unsigned int val = (unsigned int)l[(c2 * 2) * 9 + t] |
                         ((unsigned int)l[(c2 * 2 + 1) * 9 + t] << 16);
      *(unsigned int*)(dst + (size_t)t * Cout * 512 + (size_t)co * 512 + c2 * 2) = val;
    }
  } else {
    int h = tid >> 5, d = tid & 31;
    float s1 = lq1[h * 64 + d] * lk1[h * 64 + d] +
               lq1[h * 64 + d + 32] * lk1[h * 64 + d + 32];
    float s2 = lq2[h * 64 + d] * lk2[h * 64 + d] +
               lq2[h * 64 + d + 32] * lk2[h * 64 + d + 32];
    for (int m = 16; m; m >>= 1) {
      s1 += __shfl_xor(s1, m);
      s2 += __shfl_xor(s2, m);
    }
    if (d == 0) lam[h] = -(expf(s1) - expf(s2) + 0.2f);
  }
}

// ================================================= resident-pixel conv pipeline
// MODE 0 (Q): tile 128px x 128co; pixels resident, weights 4-deep ring.
// MODE 1 (OUT): tile 128co x 64px; weights ring, pixels resident.
// 144 steps (16 ci-chunks x 9 taps), BK=32, counted vmcnt, 1 barrier/step.
// Swizzle: LDS slot p of row holds global 16B-chunk p ^ ((row>>1)&3);
// bank group = 16*(row&1) + 4*(p) -> 2-way (free) for 16 consecutive rows.
template <int MODE>
__global__ __launch_bounds__(256) void conv_main(
    const us* __restrict__ pix,   // padded pixels [B][4356][512]
    const us* __restrict__ wp,    // [9][Cout][512]
    us* __restrict__ outb, float* __restrict__ outf) {
  constexpr int NR = (MODE == 0) ? 4 : 2;
  constexpr int Cout = (MODE == 0) ? 1024 : 512;
  constexpr int RROWS = (MODE == 0) ? 264 : 198;   // 4 (2) padded rows x 66
  constexpr int AROUNDS = (MODE == 0) ? 5 : 4;     // 64-row stage rounds (clamped)
  int bid = blockIdx.x;                            // 512 blocks
  int v = (bid & 7) * 64 + (bid >> 3);             // XCD swizzle
  int b, p0, co0;
  if (MODE == 0) { p0 = ((v >> 3) & 31) * 128; co0 = (v & 7) * 128; b = v >> 8; }
  else           { p0 = (v & 63) * 64; co0 = ((v >> 6) & 3) * 128; b = v >> 8; }
  int tid = threadIdx.x;
  int wave = tid >> 6, lane = tid & 63, l15 = lane & 15, hi4 = lane >> 4;
  int wr = wave >> 1, wc = wave & 1;

  __shared__ __align__(16) us Dbuf[4][128 * 32];                    // weight ring, 32 KB
  __shared__ __align__(16) us Res[(MODE == 0 ? 320 : 256) * 32];    // pixel region

  f32x4 acc[4][NR];
#pragma unroll
  for (int m = 0; m < 4; ++m)
#pragma unroll
    for (int n = 0; n < NR; ++n) acc[m][n] = (f32x4){0.f, 0.f, 0.f, 0.f};

  int y0 = p0 >> 6;
  const us* resg = pix + ((size_t)b * 4356 + (size_t)y0 * 66) * 512;
  int srow = wave * 16 + (lane >> 2);   // staging row within 64-row round
  int sg = lane & 3;                    // staging ci-group (linear dest)

  auto stageRes = [&](int c) {
#pragma unroll
    for (int ar = 0; ar < AROUNDS; ++ar) {
      int row = ar * 64 + srow;
      int rowc = row < RROWS ? row : RROWS - 1;   // clamp: uniform instr count
      gload16(resg + (size_t)rowc * 512 + c * 32 + ((sg ^ ((rowc >> 1) & 3)) * 8),
              &Res[(ar * 64 + wave * 16) * 32]);
    }
  };
  auto stageD = [&](int buf, int t, int c) {
#pragma unroll
    for (int dr = 0; dr < 2; ++dr) {
      int row = dr * 64 + srow;
      gload16(wp + ((size_t)t * Cout + co0 + row) * 512 + c * 32 +
                  ((sg ^ ((row >> 1) & 3)) * 8),
              &Dbuf[buf][(dr * 64 + wave * 16) * 32]);
    }
  };

  stageRes(0);
  stageD(0, 0, 0);
  stageD(1, 1, 0);

  for (int c = 0; c < 16; ++c) {
#pragma unroll
    for (int t = 0; t < 9; ++t) {
      int s = c * 9 + t;
      int sn = s + 2;
      if (sn < 144) stageD((c + t + 2) & 3, sn % 9, sn / 9);
      if (s == 143)
        asm volatile("s_waitcnt vmcnt(0)" ::: "memory");
      else if (s == 142 || (t == 0 && s))
        asm volatile("s_waitcnt vmcnt(2)" ::: "memory");
      else
        asm volatile("s_waitcnt vmcnt(4)" ::: "memory");
      __builtin_amdgcn_s_barrier();
      __builtin_amdgcn_sched_barrier(0);

      int ky = (t * 11) >> 5, kx = t - ky * 3;
      const us* db = &Dbuf[(c + t) & 3][0];
      short8 af[4], bf[NR];
      if (MODE == 0) {
#pragma unroll
        for (int m = 0; m < 4; ++m) {
          int row = (wr + ky) * 66 + m * 16 + l15 + kx;
          af[m] = *(const short8*)&Res[row * 32 + ((hi4 ^ ((row >> 1) & 3)) * 8)];
        }
#pragma unroll
        for (int n = 0; n < NR; ++n) {
          int row = wc * 64 + n * 16 + l15;
          bf[n] = *(const short8*)(db + row * 32 + ((hi4 ^ ((row >> 1) & 3)) * 8));
        }
      } else {
#pragma unroll
        for (int m = 0; m < 4; ++m) {
          int row = wr * 64 + m * 16 + l15;
          af[m] = *(const short8*)(db + row * 32 + ((hi4 ^ ((row >> 1) & 3)) * 8));
        }
#pragma unroll
        for (int n = 0; n < NR; ++n) {
          int row = ky * 66 + wc * 32 + n * 16 + l15 + kx;
          bf[n] = *(const short8*)&Res[row * 32 + ((hi4 ^ ((row >> 1) & 3)) * 8)];
        }
      }
#pragma unroll
      for (int m = 0; m < 4; ++m)
#pragma unroll
        for (int n = 0; n < NR; ++n)
          acc[m][n] = __builtin_amdgcn_mfma_f32_16x16x32_bf16(af[m], bf[n], acc[m][n], 0, 0, 0);

      if (t == 8 && c < 15) {
        __builtin_amdgcn_s_barrier();        // all waves done reading Res(c)
        __builtin_amdgcn_sched_barrier(0);
        stageRes(c + 1);
      }
    }
  }

  if (MODE == 0) {
    // RoPE epilogue: pairs (2j,2j+1) along co sit in adjacent lanes
    int par = lane & 1;
#pragma unroll
    for (int n = 0; n < NR; ++n) {
      int co = co0 + wc * 64 + n * 16 + l15;
      int j = (co & 127) >> 1;
      float th = exp2f(-(float)j * 0.20762050593f);
      float sth, cth;
      sincosf(th, &sth, &cth);
#pragma unroll
      for (int m = 0; m < 4; ++m) {
        int pxb = p0 + wr * 64 + m * 16 + hi4 * 4;
        float s0, c0;
        sincosf((float)pxb * th, &s0, &c0);
#pragma unroll
        for (int r = 0; r < 4; ++r) {
          float xv = acc[m][n][r];
          float ov = __shfl_xor(xv, 1);
          float y = par ? fmaf(ov, s0, xv * c0) : fmaf(xv, c0, -ov * s0);
          outb[((size_t)b * 4096 + (pxb + r)) * 1024 + co] = f2bf(y);
          float c1 = c0 * cth - s0 * sth;
          s0 = fmaf(c0, sth, s0 * cth);
          c0 = c1;
        }
      }
    }
  } else {
#pragma unroll
    for (int m = 0; m < 4; ++m)
#pragma unroll
      for (int n = 0; n < NR; ++n)
#pragma unroll
        for (int r = 0; r < 4; ++r) {
          int co = co0 + wr * 64 + m * 16 + hi4 * 4 + r;
          int px = p0 + wc * 32 + n * 16 + l15;
          outf[((size_t)b * 512 + co) * 4096 + px] = acc[m][n][r];
        }
  }
}

// ================================================= 64^2 conv body (K,V), 32KB LDS
template <int TRANS_OUT, int ROPE>
__device__ __forceinline__ void conv64_body(
    const us* __restrict__ inT, const us* __restrict__ wp,
    us* __restrict__ out, int Cout, int logCoT, int bid, int ngrid, us* sh) {
  int nchunk = ngrid >> 3;
  int v = (bid & 7) * nchunk + (bid >> 3);
  int yt = v & 15;
  int cot = (v >> 4) & ((1 << logCoT) - 1);
  int b = v >> (4 + logCoT);
  int p0 = yt * 64, co0 = cot * 64;
  const int W = 32, logW = 5, padW = 34, HW = 1024;
  int tid = threadIdx.x;
  int wave = tid >> 6, lane = tid & 63, l15 = lane & 15, hi4 = lane >> 4;
  f32x4 acc[4];
#pragma unroll
  for (int i = 0; i < 4; ++i) acc[i] = (f32x4){0.f, 0.f, 0.f, 0.f};

  int arow[2], brow[2];
#pragma unroll
  for (int c = 0; c < 2; ++c) {
    int row = (wave * 2 + c) * 8 + (lane >> 3);
    int g = (lane & 7) ^ (row & 7);
    int px = p0 + row;
    int y = px >> logW, x = px & (W - 1);
    arow[c] = (y * padW + x) * 512 + g * 8;
    brow[c] = (co0 + row) * 512 + g * 8;
  }
  int gb[2];
#pragma unroll
  for (int ks = 0; ks < 2; ++ks) gb[ks] = ((ks * 4 + hi4) ^ (l15 & 7)) * 8;

  const us* abase = inT + (size_t)b * padW * padW * 512;

  auto stage = [&](int buf, int s) {
    int tn = s >> 3, ci = (s & 7) << 6;
    int ky = (tn * 11) >> 5, kx = tn - ky * 3;
    const us* as = abase + (ky * padW + kx) * 512 + ci;
    const us* bs = wp + (size_t)tn * Cout * 512 + ci;
    us* la = sh + buf * 8192;
    us* lb = la + 4096;
#pragma unroll
    for (int c = 0; c < 2; ++c) {
      gload16(as + arow[c], la + (wave * 2 + c) * 512);
      gload16(bs + brow[c], lb + (wave * 2 + c) * 512);
    }
  };

  stage(0, 0);
  __syncthreads();
  for (int s = 0; s < 72; ++s) {
    int cur = s & 1;
    if (s < 71) stage(cur ^ 1, s + 1);
    const us* la = sh + cur * 8192;
    const us* lb = la + 4096;
#pragma unroll
    for (int ks = 0; ks < 2; ++ks) {
      short8 bf = *(const short8*)(lb + (16 * wave + l15) * 64 + gb[ks]);
#pragma unroll
      for (int i = 0; i < 4; ++i) {
        short8 af = *(const short8*)(la + (i * 16 + l15) * 64 + gb[ks]);
        acc[i] = __builtin_amdgcn_mfma_f32_16x16x32_bf16(af, bf, acc[i], 0, 0, 0);
      }
    }
    __syncthreads();
  }
  if (ROPE) {
    int co = co0 + 16 * wave + l15;
    int j = (co & 127) >> 1;
    float th = exp2f(-(float)j * 0.20762050593f);
    float sth, cth;
    sincosf(th, &sth, &cth);
    int par = lane & 1;
#pragma unroll
    for (int i = 0; i < 4; ++i) {
      int pxb = p0 + i * 16 + hi4 * 4;
      float s0, c0;
      sincosf((float)pxb * th, &s0, &c0);
#pragma unroll
      for (int r = 0; r < 4; ++r) {
        float xv = acc[i][r];
        float ov = __shfl_xor(xv, 1);
        float y = par ? fmaf(ov, s0, xv * c0) : fmaf(xv, c0, -ov * s0);
        out[((size_t)b * HW + (pxb + r)) * Cout + co] = f2bf(y);
        float c1 = c0 * cth - s0 * sth;
        s0 = fmaf(c0, sth, s0 * cth);
        c0 = c1;
      }
    }
  } else {
#pragma unroll
    for (int i = 0; i < 4; ++i)
#pragma unroll
      for (int r = 0; r < 4; ++r) {
        int px = TRANS_OUT ? (p0 + (hi4 * 4 + r) * 4 + i)  // sigma(k)=(k%16)*4+k/16
                           : (p0 + i * 16 + hi4 * 4 + r);
        int co = co0 + 16 * wave + l15;
        us val = f2bf(acc[i][r]);
        if (TRANS_OUT)
          out[((size_t)b * Cout + co) * HW + px] = val;
        else
          out[((size_t)b * HW + px) * Cout + co] = val;
      }
  }
}

__global__ __launch_bounds__(256) void conv64_all(
    const us* __restrict__ cpadT, const us* __restrict__ wkp,
    const us* __restrict__ wvp, us* __restrict__ kb, us* __restrict__ vT) {
  __shared__ __align__(16) us sh[2][2][64][64];  // 32 KB
  int bid = blockIdx.x;
  if (bid < 256) conv64_body<0, 1>(cpadT, wkp, kb, 512, 3, bid, 256, &sh[0][0][0][0]);
  else           conv64_body<1, 0>(cpadT, wvp, vT, 256, 2, bid - 256, 128, &sh[0][0][0][0]);
}

// ================================================= differential GQA attention + RMSNorm
__global__ __launch_bounds__(256) void attn_kernel(
    const us* __restrict__ qb, const us* __restrict__ kb,
    const us* __restrict__ vT, const float* __restrict__ lam,
    us* __restrict__ apad) {
  int qt = blockIdx.x, h = blockIdx.y, b = blockIdx.z;
  int kvh = h >> 1;
  int tid = threadIdx.x;
  int wave = tid >> 6, lane = tid & 63, l15 = lane & 15, hi4 = lane >> 4;
  __shared__ __align__(16) us Klds[2][8192];   // [buf][64 k rows][128 d]
  __shared__ __align__(16) us Vlds[2][4096];   // [buf][64 dv rows][64 k']
  __shared__ __align__(16) us Plds[4][16][72];

  int q0 = qt * 128;
  short8 qf[2][2][2];  // [mf][m][ks]
  {
    const us* qsrc =
        qb + ((size_t)(b * 4096 + q0 + wave * 32 + l15)) * 1024 + h * 128 + hi4 * 8;
#pragma unroll
    for (int mf = 0; mf < 2; ++mf)
#pragma unroll
      for (int m = 0; m < 2; ++m)
#pragma unroll
        for (int ks = 0; ks < 2; ++ks)
          qf[mf][m][ks] = *(const short8*)(qsrc + mf * 16384 + m * 64 + ks * 32);
  }

  float sumd[2][2][4];
  f32x4 accO[2][2][4];
#pragma unroll
  for (int mf = 0; mf < 2; ++mf)
#pragma unroll
    for (int m = 0; m < 2; ++m)
#pragma unroll
      for (int r = 0; r < 4; ++r) {
        sumd[mf][m][r] = 0.f;
        accO[mf][m][r] = (f32x4){0.f, 0.f, 0.f, 0.f};
      }
  float lamh = lam[h];

  const us* kbase0 = kb + (size_t)b * 524288 + kvh * 128;
  const us* vbase0 = vT + ((size_t)(b * 256 + kvh * 64)) * 1024;
  int krow[4], vrow[2];
#pragma unroll
  for (int c = 0; c < 4; ++c) {
    int row = (wave * 4 + c) * 4 + hi4;
    int g = (l15 & 8) | ((l15 & 7) ^ (row & 7));
    krow[c] = row * 512 + g * 8;
  }
#pragma unroll
  for (int c = 0; c < 2; ++c) {
    int row = (wave * 2 + c) * 8 + (lane >> 3);
    int g = (lane & 7) ^ (row & 7);
    vrow[c] = row * 1024 + g * 8;
  }
  int kg0[2], kg1[2], vg[2];
#pragma unroll
  for (int m = 0; m < 2; ++m) {
    kg0[m] = (m * 8 | (hi4 ^ (l15 & 7))) * 8;
    kg1[m] = (m * 8 | ((4 + hi4) ^ (l15 & 7))) * 8;
  }
#pragma unroll
  for (int ks = 0; ks < 2; ++ks) vg[ks] = ((ks * 4 + hi4) ^ (l15 & 7)) * 8;

  auto stage = [&](int buf, int kt2) {
    const us* kk = kbase0 + (size_t)kt2 * 32768;
    const us* vv = vbase0 + kt2 * 64;
#pragma unroll
    for (int c = 0; c < 4; ++c)
      gload16(kk + krow[c], &Klds[buf][(wave * 4 + c) * 512]);
#pragma unroll
    for (int c = 0; c < 2; ++c)
      gload16(vv + vrow[c], &Vlds[buf][(wave * 2 + c) * 512]);
  };

  const float cexp = 0.18033688f;  // 0.125 * log2(e)
  stage(0, 0);
  for (int kt = 0; kt < 16; ++kt) {
    int cur = kt & 1;
    if (kt < 15) {
      stage(cur ^ 1, kt + 1);
      asm volatile("s_waitcnt vmcnt(6)" ::: "memory");
    } else {
      asm volatile("s_waitcnt vmcnt(0)" ::: "memory");
    }
    __builtin_amdgcn_s_barrier();
    __builtin_amdgcn_sched_barrier(0);

    short8 vf[2][4];
#pragma unroll
    for (int ks = 0; ks < 2; ++ks)
#pragma unroll
      for (int nf = 0; nf < 4; ++nf)
        vf[ks][nf] = *(const short8*)&Vlds[cur][(nf * 16 + l15) * 64 + vg[ks]];

#pragma unroll
    for (int m = 0; m < 2; ++m) {
      short8 kf[4][2];
#pragma unroll
      for (int nf = 0; nf < 4; ++nf) {
        kf[nf][0] = *(const short8*)&Klds[cur][(nf * 16 + l15) * 128 + kg0[m]];
        kf[nf][1] = *(const short8*)&Klds[cur][(nf * 16 + l15) * 128 + kg1[m]];
      }
#pragma unroll
      for (int mf = 0; mf < 2; ++mf) {
        f32x4 s[4];
        __builtin_amdgcn_s_setprio(1);
#pragma unroll
        for (int nf = 0; nf < 4; ++nf) {
          f32x4 z = (f32x4){0.f, 0.f, 0.f, 0.f};
          z = __builtin_amdgcn_mfma_f32_16x16x32_bf16(qf[mf][m][0], kf[nf][0], z, 0, 0, 0);
          z = __builtin_amdgcn_mfma_f32_16x16x32_bf16(qf[mf][m][1], kf[nf][1], z, 0, 0, 0);
          s[nf] = z;
        }
        __builtin_amdgcn_s_setprio(0);
#pragma unroll
        for (int r = 0; r < 4; ++r) {
          float p0 = fast_exp2(s[0][r] * cexp);
          float p1 = fast_exp2(s[1][r] * cexp);
          float p2 = fast_exp2(s[2][r] * cexp);
          float p3 = fast_exp2(s[3][r] * cexp);
          sumd[mf][m][r] += (p0 + p1) + (p2 + p3);
          unsigned int w0 = cvt_pk_bf16(p0, p1);
          unsigned int w1 = cvt_pk_bf16(p2, p3);
          *(uint2*)&Plds[wave][hi4 * 4 + r][l15 * 4] = make_uint2(w0, w1);
        }
        __builtin_amdgcn_s_setprio(1);
#pragma unroll
        for (int ks = 0; ks < 2; ++ks) {
          short8 pf = *(const short8*)&Plds[wave][l15][ks * 32 + hi4 * 8];
#pragma unroll
          for (int nf = 0; nf < 4; ++nf)
            accO[mf][m][nf] =
                __builtin_amdgcn_mfma_f32_16x16x32_bf16(pf, vf[ks][nf], accO[mf][m][nf], 0, 0, 0);
        }
        __builtin_amdgcn_s_setprio(0);
      }
    }
    asm volatile("s_waitcnt lgkmcnt(0)" ::: "memory");
    __builtin_amdgcn_s_barrier();
    __builtin_amdgcn_sched_barrier(0);
  }

  // epilogue: denom reduce, combine mults, RMSNorm, scale 0.8
#pragma unroll
  for (int mf = 0; mf < 2; ++mf)
#pragma unroll
    for (int m = 0; m < 2; ++m)
#pragma unroll
      for (int r = 0; r < 4; ++r) {
        float sx = sumd[mf][m][r];
        sx += __shfl_xor(sx, 1);
        sx += __shfl_xor(sx, 2);
        sx += __shfl_xor(sx, 4);
        sx += __shfl_xor(sx, 8);
        sumd[mf][m][r] = sx;
      }
#pragma unroll
  for (int mf = 0; mf < 2; ++mf)
#pragma unroll
    for (int r = 0; r < 4; ++r) {
      float inv0 = 1.f / sumd[mf][0][r];
      float inv1 = lamh / sumd[mf][1][r];
      float comb[4];
      float ss = 0.f;
#pragma unroll
      for (int nf = 0; nf < 4; ++nf) {
        comb[nf] = accO[mf][0][nf][r] * inv0 + accO[mf][1][nf][r] * inv1;
        ss += comb[nf] * comb[nf];
      }
      ss += __shfl_xor(ss, 1);
      ss += __shfl_xor(ss, 2);
      ss += __shfl_xor(ss, 4);
      ss += __shfl_xor(ss, 8);
      float sc = rsqrtf(ss * (1.f / 64.f) + 1e-8f) * 0.8f;
      int q = q0 + wave * 32 + mf * 16 + hi4 * 4 + r;
      int y = q >> 6, x = q & 63;
      size_t oaddr = ((size_t)b * 4356 + (size_t)(y + 1) * 66 + (x + 1)) * 512 + h * 64;
#pragma unroll
      for (int nf = 0; nf < 4; ++nf) apad[oaddr + nf * 16 + l15] = f2bf(comb[nf] * sc);
    }
}

// ============================================================== launch
extern "C" void kernel_launch(void* const* d_in, const int* in_sizes, int n_in,
                              void* d_out, int out_size, void* d_ws, size_t ws_size,
                              hipStream_t stream) {
  const float* x     = (const float*)d_in[0];
  const float* cross = (const float*)d_in[1];
  const float* wq    = (const float*)d_in[2];
  const float* wk    = (const float*)d_in[3];
  const float* wv    = (const float*)d_in[4];
  const float* wo    = (const float*)d_in[5];
  const float* lq1   = (const float*)d_in[6];
  const float* lq2   = (const float*)d_in[7];
  const float* lk1   = (const float*)d_in[8];
  const float* lk2   = (const float*)d_in[9];
  float* out = (float*)d_out;

  char* ws = (char*)d_ws;
  size_t off = 0;
  auto nxt = [&](size_t bytes) { char* p = ws + off; off += bytes; return p; };
  us* xpadT = (us*)nxt(8921088);   // [2][4356][512] bf16
  us* cpadT = (us*)nxt(2367488);   // [2][1156][512] bf16
  us* apad  = (us*)nxt(8921088);   // [2][4356][512] bf16
  us* wqp = (us*)nxt(9437184);     // [9][1024][512]
  us* wkp = (us*)nxt(4718592);     // [9][512][512]
  us* wvp = (us*)nxt(2359296);     // [9][256][512]
  us* wop = (us*)nxt(4718592);     // [9][512][512]
  us* qb  = (us*)nxt(16777216);    // [2][4096][1024] (rope'd)
  us* kb  = (us*)nxt(2097152);     // [2][1024][512]  (rope'd)
  us* vT  = (us*)nxt(1048576);     // [2][256][1024] (sigma-permuted along k)
  float* lam = (float*)nxt(256);   // [8]
  (void)ws_size; (void)in_sizes; (void)n_in; (void)out_size;

  prep_all<<<4167, 256, 0, stream>>>(x, cross, wq, wk, wv, wo,
                                     lq1, lq2, lk1, lk2,
                                     xpadT, cpadT, apad, wqp, wkp, wvp, wop, lam);
  conv64_all<<<384, 256, 0, stream>>>(cpadT, wkp, wvp, kb, vT);
  conv_main<0><<<512, 256, 0, stream>>>(xpadT, wqp, qb, nullptr);
  attn_kernel<<<dim3(32, 8, 2), 256, 0, stream>>>(qb, kb, vT, lam, apad);
  conv_main<1><<<512, 256, 0, stream>>>(apad, wop, nullptr, out);
}